// Round 6
// baseline (125.035 us; speedup 1.0000x reference)
//
#include <hip/hip_runtime.h>

#define N_FEAT 1024
#define N_LAYER 4

typedef float floatx4 __attribute__((ext_vector_type(4)));

__device__ __forceinline__ float dot4(const float4 a, const float4 b) {
  return fmaf(a.x, b.x, fmaf(a.y, b.y, fmaf(a.z, b.z, a.w * b.w)));
}

// K1: p[row][i] = <x_row, w_i>. Grid-stride wave-per-row; w hoisted into regs
// once per wave (zero weight re-reads). Pure 64MB read stream + tiny p write.
__global__ __launch_bounds__(256) void k_reduce(
    const float* __restrict__ x, const float* __restrict__ weight_w,
    float* __restrict__ p, int n_rows) {
  const int wave = threadIdx.x >> 6;
  const int lane = threadIdx.x & 63;
  const int gw = blockIdx.x * 4 + wave;
  const int n_waves = gridDim.x * 4;

  float4 w[N_LAYER][4];
#pragma unroll
  for (int i = 0; i < N_LAYER; ++i)
#pragma unroll
    for (int c = 0; c < 4; ++c)
      w[i][c] = ((const float4*)(weight_w + i * N_FEAT))[c * 64 + lane];

  for (int row = gw; row < n_rows; row += n_waves) {
    const float4* xr = (const float4*)(x + (size_t)row * N_FEAT);
    float4 xv[4];
#pragma unroll
    for (int c = 0; c < 4; ++c) xv[c] = xr[c * 64 + lane];

    float pp[N_LAYER] = {0.f, 0.f, 0.f, 0.f};
#pragma unroll
    for (int c = 0; c < 4; ++c)
#pragma unroll
      for (int i = 0; i < N_LAYER; ++i) pp[i] += dot4(xv[c], w[i][c]);

#pragma unroll
    for (int off = 32; off > 0; off >>= 1)
#pragma unroll
      for (int i = 0; i < N_LAYER; ++i) pp[i] += __shfl_xor(pp[i], off, 64);

    if (lane == 0) {
      float4 pv = make_float4(pp[0], pp[1], pp[2], pp[3]);
      ((float4*)p)[row] = pv;
    }
  }
}

// K2: pure elementwise stream: out = A(row)*x + csum. Per-wave prologue
// recomputes e_i (butterfly) and csum slice from L2-hot w/b; then grid-stride
// copy-shaped main loop (load x -> fma -> nt store).
__global__ __launch_bounds__(256) void k_apply(
    const float* __restrict__ x, const float* __restrict__ weight_w,
    const float* __restrict__ weight_b, const float* __restrict__ p,
    float* __restrict__ out, int n_rows) {
  const int wave = threadIdx.x >> 6;
  const int lane = threadIdx.x & 63;
  const int gw = blockIdx.x * 4 + wave;
  const int n_waves = gridDim.x * 4;

  float4 csum[4];
  float e[N_LAYER] = {0.f, 0.f, 0.f, 0.f};
#pragma unroll
  for (int c = 0; c < 4; ++c) {
    float4 w[N_LAYER];
#pragma unroll
    for (int i = 0; i < N_LAYER; ++i)
      w[i] = ((const float4*)(weight_w + i * N_FEAT))[c * 64 + lane];
    float4 cum = make_float4(0.f, 0.f, 0.f, 0.f);
#pragma unroll
    for (int i = 0; i < N_LAYER; ++i) {
      if (i > 0) e[i] += dot4(cum, w[i]);
      float4 b = ((const float4*)(weight_b + i * N_FEAT))[c * 64 + lane];
      cum.x += b.x; cum.y += b.y; cum.z += b.z; cum.w += b.w;
    }
    csum[c] = cum;
  }
#pragma unroll
  for (int off = 32; off > 0; off >>= 1)
#pragma unroll
    for (int i = 1; i < N_LAYER; ++i) e[i] += __shfl_xor(e[i], off, 64);

  for (int row = gw; row < n_rows; row += n_waves) {
    const float4 pv = ((const float4*)p)[row];  // same addr all lanes: broadcast
    float A = 1.f;
    A = fmaf(A, pv.x, A);            // + e[0]==0
    A = fmaf(A, pv.y, A + e[1]);
    A = fmaf(A, pv.z, A + e[2]);
    A = fmaf(A, pv.w, A + e[3]);

    const float4* xr = (const float4*)(x + (size_t)row * N_FEAT);
    floatx4* orow = (floatx4*)(out + (size_t)row * N_FEAT);
#pragma unroll
    for (int c = 0; c < 4; ++c) {
      float4 xv = xr[c * 64 + lane];
      floatx4 o;
      o.x = fmaf(xv.x, A, csum[c].x);
      o.y = fmaf(xv.y, A, csum[c].y);
      o.z = fmaf(xv.z, A, csum[c].z);
      o.w = fmaf(xv.w, A, csum[c].w);
      __builtin_nontemporal_store(o, &orow[c * 64 + lane]);
    }
  }
}

extern "C" void kernel_launch(void* const* d_in, const int* in_sizes, int n_in,
                              void* d_out, int out_size, void* d_ws, size_t ws_size,
                              hipStream_t stream) {
  const float* x = (const float*)d_in[0];
  const float* ww = (const float*)d_in[1];
  const float* wb = (const float*)d_in[2];
  float* out = (float*)d_out;
  float* p = (float*)d_ws;  // 16384 rows x 4 floats = 256 KB scratch

  int n_rows = in_sizes[0] / N_FEAT;  // 16384
  // 2048 blocks = 8 blocks/CU backfill; 8192 waves -> 2 rows/wave grid-stride
  k_reduce<<<2048, 256, 0, stream>>>(x, ww, p, n_rows);
  k_apply<<<2048, 256, 0, stream>>>(x, ww, wb, p, out, n_rows);
}